// Round 12
// baseline (48.462 us; speedup 1.0000x reference)
//
#include <hip/hip_runtime.h>
#include <math.h>

// Problem constants
#define LN 512
#define RN 4096
#define EN 32
#define FN 64

// Main tiling: 128(l) x 128(r) pair tile per block, 512 threads = 8 waves.
// Wave tile = 32(l) x 64(r) = 2x4 grid of 16x16 MFMA tiles.
// EH=8 -> grid (32,4,4) = 512 blocks = 2 blocks/CU (LDS-capped: 64KB dbuf).
// ROLLED e-loop + no setprio (round-11 A/B isolated these as the regression).
#define BLT 128
#define BRT 128
#define EH  8
#define NBLOCKS ((RN / BRT) * (LN / BLT) * (EN / EH))   // 512

#define SQK      4.804489631554082f    // sqrt(16*log2(e))
#define MU_STEP  (8.0f / 31.0f)
#define SDLT     (SQK * MU_STEP)       // per-e decrement of t' = sqrtK*(d-mu_e)

typedef _Float16 half8 __attribute__((ext_vector_type(8)));  // MFMA A/B frag (4 VGPR)
typedef __attribute__((ext_vector_type(4))) float f32x4;     // MFMA C/D frag

// LDS: 2 buffers, each = A plane (128 rows x 128B) + B plane (128 rows x 128B)
#define BUFBYTES 32768
#define BPLANE   16384

// d_ws layout (bytes)
#define WS_LIG 0                      // 512*32*64*2  = 2 MB f16 swizzled
#define WS_REC (2u * 1024 * 1024)     // 4096*32*64*2 = 16 MB f16 swizzled
#define WS_PART (18u * 1024 * 1024)   // partials (512 floats)
#define WS_CNT  (WS_PART + NBLOCKS * 4)

// 16-byte granules per feature row: FN*2/16 = 8.  Row stride = EN*128 = 4096 B.
#define LCHUNKS (LN * EN * 8)   // 131072
#define RCHUNKS (RN * EN * 8)   // 1048576

typedef const __attribute__((address_space(1))) unsigned int* gas_ptr;
typedef __attribute__((address_space(3))) unsigned int* las_ptr;
#define GL16(g, l) __builtin_amdgcn_global_load_lds((gas_ptr)(g), (las_ptr)(l), 16, 0, 0)

// ---------------- converter: fp32 -> f16 (RTE), granule-XOR pre-swizzle ----------------
// Granule at ((row*EN+e)*8 + (gf ^ (row&7)))*16B holds f16 of f = gf*8..gf*8+7.
// A linear 128-row copy into LDS reproduces the in-LDS XOR-swizzled layout
// (verified rounds 8/10/11: absmax 0.0625, conflicts 0). Also zeroes the
// completion counter for this launch.
__global__ __launch_bounds__(256) void ff_convert(
    const float* __restrict__ lig_feat, const float* __restrict__ rec_feat,
    unsigned short* __restrict__ lig_swz, unsigned short* __restrict__ rec_swz,
    unsigned int* __restrict__ done)
{
    if (blockIdx.x == 0 && threadIdx.x == 0) *done = 0u;

    int idx = blockIdx.x * 256 + threadIdx.x;
    const float* src;
    unsigned short* dst;
    if (idx < LCHUNKS) {
        src = lig_feat; dst = lig_swz;
    } else {
        idx -= LCHUNKS;
        src = rec_feat; dst = rec_swz;
    }
    const int row = idx >> 8;         // 256 granules per row (EN*8)
    const int e   = (idx >> 3) & 31;
    const int gf  = idx & 7;

    const float* s = src + (((size_t)row * EN + e) * FN + gf * 8);
    const float4 v0 = *(const float4*)s;
    const float4 v1 = *(const float4*)(s + 4);

    const unsigned short q0 = __builtin_bit_cast(unsigned short, (_Float16)v0.x);
    const unsigned short q1 = __builtin_bit_cast(unsigned short, (_Float16)v0.y);
    const unsigned short q2 = __builtin_bit_cast(unsigned short, (_Float16)v0.z);
    const unsigned short q3 = __builtin_bit_cast(unsigned short, (_Float16)v0.w);
    const unsigned short q4 = __builtin_bit_cast(unsigned short, (_Float16)v1.x);
    const unsigned short q5 = __builtin_bit_cast(unsigned short, (_Float16)v1.y);
    const unsigned short q6 = __builtin_bit_cast(unsigned short, (_Float16)v1.z);
    const unsigned short q7 = __builtin_bit_cast(unsigned short, (_Float16)v1.w);
    uint4 o;
    o.x = (unsigned)q0 | ((unsigned)q1 << 16);
    o.y = (unsigned)q2 | ((unsigned)q3 << 16);
    o.z = (unsigned)q4 | ((unsigned)q5 << 16);
    o.w = (unsigned)q6 | ((unsigned)q7 << 16);

    const size_t dpos = (((size_t)row * EN + e) * 8 + (gf ^ (row & 7))) * 8; // ushort units
    *(uint4*)(dst + dpos) = o;
}

// ---------------- main kernel: dbuf GL16 pipeline + fused final reduce ----------------
__global__ __launch_bounds__(512, 1) void ff_mfma(
    const unsigned short* __restrict__ lig_swz,  // [L][E][8 swz granules][8 f16]
    const unsigned short* __restrict__ rec_swz,  // [R][E][8 swz granules][8 f16]
    const float* __restrict__ lig_coord,         // [L][3]
    const float* __restrict__ rec_coord,         // [R][3]
    float* __restrict__ partial,
    unsigned int* __restrict__ done,
    float* __restrict__ out)
{
    __shared__ char lds[2 * BUFBYTES];
    __shared__ int isLast;

    const int tid  = threadIdx.x;
    const int lane = tid & 63;
    const int w    = tid >> 6;         // 0..7
    const int wl   = (w & 3) * 2;      // wave's base l-tile (0,2,4,6) of 8
    const int wr   = (w >> 2) * 4;     // wave's base r-tile (0,4) of 8
    const int lrow = lane & 15;        // A-row / B-col within 16x16 tile
    const int lk   = lane >> 4;        // k-group 0..3

    const int l0 = blockIdx.y * BLT;
    const int r0 = blockIdx.x * BRT;
    const int e0 = blockIdx.z * EH;

    // per-thread staging source offsets (hoisted)
    int soff[2];
    #pragma unroll
    for (int k = 0; k < 2; ++k) {
        const int idx = k * 512 + tid;
        soff[k] = (idx >> 3) * (EN * 128) + (idx & 7) * 16;
    }
    const char* ligb = (const char*)lig_swz + (size_t)l0 * (EN * 128);
    const char* recb = (const char*)rec_swz + (size_t)r0 * (EN * 128);

#define STAGE(b, e_) do {                                                   \
        const int ebyte_ = (e_) * 128;                                      \
        _Pragma("unroll")                                                   \
        for (int k_ = 0; k_ < 2; ++k_) {                                    \
            const int idx_ = k_ * 512 + tid;                                \
            GL16(ligb + soff[k_] + ebyte_, lds + (b) * BUFBYTES + idx_ * 16);            \
            GL16(recb + soff[k_] + ebyte_, lds + (b) * BUFBYTES + BPLANE + idx_ * 16);   \
        }                                                                   \
    } while (0)

    // ---- distances -> pre-scaled t' = SQK*(d - mu_{e0}), reused across EH ----
    // C/D layout (m89-verified): col = lane&15 (-> r), row = (lane>>4)*4 + reg (-> l)
    float rcx[4], rcy[4], rcz[4];
    #pragma unroll
    for (int tj = 0; tj < 4; ++tj) {
        const int r = r0 + (wr + tj) * 16 + lrow;
        rcx[tj] = rec_coord[r * 3 + 0];
        rcy[tj] = rec_coord[r * 3 + 1];
        rcz[tj] = rec_coord[r * 3 + 2];
    }
    const float mu0s = -SQK * MU_STEP * (float)e0;   // -SQK*mu_{e0}
    float t[2][4][4];   // [ti][tj][reg]
    #pragma unroll
    for (int ti = 0; ti < 2; ++ti) {
        #pragma unroll
        for (int i = 0; i < 4; ++i) {
            const int l = l0 + (wl + ti) * 16 + lk * 4 + i;
            const float lx = lig_coord[l * 3 + 0];
            const float ly = lig_coord[l * 3 + 1];
            const float lz = lig_coord[l * 3 + 2];
            #pragma unroll
            for (int tj = 0; tj < 4; ++tj) {
                const float dx = lx - rcx[tj];
                const float dy = ly - rcy[tj];
                const float dz = lz - rcz[tj];
                const float d = sqrtf(fmaf(dx, dx, fmaf(dy, dy, dz * dz)));
                t[ti][tj][i] = fmaf(SQK, d, mu0s);
            }
        }
    }

    // ---- pipeline prologue: stage e0 into buf0 ----
    STAGE(0, e0);
    __syncthreads();   // auto vmcnt(0): buf0 valid

    float usum = 0.0f;

    for (int ee = 0; ee < EH; ++ee) {    // ROLLED (round-11 unroll regressed)
        const int cur = ee & 1;
        const int e   = e0 + ee;

        // ---- issue next-e stage into the other buffer (flies over compute) ----
        if (ee + 1 < EH) STAGE(cur ^ 1, e + 1);

        // ---- compute from buf[cur] ----
        const char* base = lds + cur * BUFBYTES;

        f32x4 acc[2][4];
        #pragma unroll
        for (int ti = 0; ti < 2; ++ti)
            #pragma unroll
            for (int tj = 0; tj < 4; ++tj)
                acc[ti][tj] = (f32x4){0.f, 0.f, 0.f, 0.f};

        #pragma unroll
        for (int kc = 0; kc < 2; ++kc) {
            const int inrow = (kc * 64 + lk * 16) ^ ((lrow & 7) << 4);
            half8 af[2], bf_[4];
            #pragma unroll
            for (int tt = 0; tt < 2; ++tt) {
                const int arow = (wl + tt) * 16 + lrow;
                af[tt] = *(const half8*)(base + arow * 128 + inrow);
            }
            #pragma unroll
            for (int tt = 0; tt < 4; ++tt) {
                const int brow = (wr + tt) * 16 + lrow;
                bf_[tt] = *(const half8*)(base + BPLANE + brow * 128 + inrow);
            }
            #pragma unroll
            for (int ti = 0; ti < 2; ++ti) {
                #pragma unroll
                for (int tj = 0; tj < 4; ++tj) {
                    acc[ti][tj] = __builtin_amdgcn_mfma_f32_16x16x32_f16(
                        af[ti], bf_[tj], acc[ti][tj], 0, 0, 0);
                }
            }
        }

        // ---- rbf weight + accumulate: u = t'^2; w = exp2(-u); fma; t' -= SDLT ----
        #pragma unroll
        for (int ti = 0; ti < 2; ++ti) {
            #pragma unroll
            for (int tj = 0; tj < 4; ++tj) {
                #pragma unroll
                for (int i = 0; i < 4; ++i) {
                    const float u = t[ti][tj][i] * t[ti][tj][i];
                    const float wgt = __builtin_amdgcn_exp2f(-u);
                    usum = fmaf(acc[ti][tj][i], wgt, usum);
                    t[ti][tj][i] -= SDLT;
                }
            }
        }

        // one barrier per e: drains this iter's stage loads and protects buffers
        __syncthreads();
    }

    // ---- block reduction (reuse LDS; safe after the loop's final barrier) ----
    float* red = (float*)lds;
    red[tid] = usum;
    __syncthreads();
    #pragma unroll
    for (int st = 256; st > 0; st >>= 1) {
        if (tid < st) red[tid] += red[tid + st];
        __syncthreads();
    }

    // ---- fused final reduce: last-arriving block sums the partials ----
    const int bidx = (blockIdx.z * gridDim.y + blockIdx.y) * gridDim.x + blockIdx.x;
    if (tid == 0) {
        partial[bidx] = red[0];
        __threadfence();                               // release partial store
        isLast = (atomicAdd(done, 1u) == NBLOCKS - 1u);
    }
    __syncthreads();
    if (isLast) {
        __threadfence();                               // acquire all partials
        red[tid] = partial[tid];                       // 512 threads, 512 partials
        __syncthreads();
        #pragma unroll
        for (int st = 256; st > 0; st >>= 1) {
            if (tid < st) red[tid] += red[tid + st];
            __syncthreads();
        }
        if (tid == 0) out[0] = red[0] * 0.01f;
    }
#undef STAGE
}

extern "C" void kernel_launch(void* const* d_in, const int* in_sizes, int n_in,
                              void* d_out, int out_size, void* d_ws, size_t ws_size,
                              hipStream_t stream)
{
    const float* lig_feat  = (const float*)d_in[0];
    const float* rec_feat  = (const float*)d_in[1];
    const float* lig_coord = (const float*)d_in[2];
    const float* rec_coord = (const float*)d_in[3];
    float* out = (float*)d_out;

    unsigned short* lig_swz = (unsigned short*)((char*)d_ws + WS_LIG);
    unsigned short* rec_swz = (unsigned short*)((char*)d_ws + WS_REC);
    float* partial          = (float*)((char*)d_ws + WS_PART);
    unsigned int* done      = (unsigned int*)((char*)d_ws + WS_CNT);

    // 1) one-time fp32 -> swizzled f16 conversion + counter zero (BW-floor ~9 us)
    const int nChunks = LCHUNKS + RCHUNKS;           // 1,179,648
    ff_convert<<<nChunks / 256, 256, 0, stream>>>(lig_feat, rec_feat, lig_swz, rec_swz, done);

    // 2) main MFMA kernel, double-buffered pipeline, fused final reduction
    const dim3 grid(RN / BRT, LN / BLT, EN / EH);    // (32, 4, 4) = 512 blocks
    ff_mfma<<<grid, dim3(512), 0, stream>>>(lig_swz, rec_swz, lig_coord, rec_coord,
                                            partial, done, out);
}

// Round 13
// 36.323 us; speedup vs baseline: 1.3342x; 1.3342x over previous
//
#include <hip/hip_runtime.h>
#include <math.h>

// Problem constants
#define LN 512
#define RN 4096
#define EN 32
#define FN 64

// Main tiling: 128(l) x 128(r) pair tile per block, 512 threads = 8 waves.
// Wave tile = 32(l) x 64(r) = 2x4 grid of 16x16 MFMA tiles.
// EH=8 -> grid (32,4,4) = 512 blocks = 2 blocks/CU (LDS-capped: 64KB dbuf).
// Structure = round-10 exactly (3 kernels, no device-scope fences: the fused
// last-block reduce's __threadfence()s were the prime suspect for R11/12's
// +8us). Only delta vs R10: the 4-op t' epilogue (numerics proven R11/12).
#define BLT 128
#define BRT 128
#define EH  8

#define SQK      4.804489631554082f    // sqrt(16*log2(e))
#define MU_STEP  (8.0f / 31.0f)
#define SDLT     (SQK * MU_STEP)       // per-e decrement of t' = sqrtK*(d-mu_e)

typedef _Float16 half8 __attribute__((ext_vector_type(8)));  // MFMA A/B frag (4 VGPR)
typedef __attribute__((ext_vector_type(4))) float f32x4;     // MFMA C/D frag

// LDS: 2 buffers, each = A plane (128 rows x 128B) + B plane (128 rows x 128B)
#define BUFBYTES 32768
#define BPLANE   16384

// d_ws layout (bytes)
#define WS_LIG 0                      // 512*32*64*2  = 2 MB f16 swizzled
#define WS_REC (2u * 1024 * 1024)     // 4096*32*64*2 = 16 MB f16 swizzled
#define WS_PART (18u * 1024 * 1024)   // partials (512 floats)

// 16-byte granules per feature row: FN*2/16 = 8.  Row stride = EN*128 = 4096 B.
#define LCHUNKS (LN * EN * 8)   // 131072
#define RCHUNKS (RN * EN * 8)   // 1048576

typedef const __attribute__((address_space(1))) unsigned int* gas_ptr;
typedef __attribute__((address_space(3))) unsigned int* las_ptr;
#define GL16(g, l) __builtin_amdgcn_global_load_lds((gas_ptr)(g), (las_ptr)(l), 16, 0, 0)

// ---------------- converter: fp32 -> f16 (RTE), granule-XOR pre-swizzle ----------------
// Granule at ((row*EN+e)*8 + (gf ^ (row&7)))*16B holds f16 of f = gf*8..gf*8+7.
// A linear 128-row copy into LDS reproduces the in-LDS XOR-swizzled layout
// (verified rounds 8/10/11/12: absmax 0.0625, conflicts 0).
__global__ __launch_bounds__(256) void ff_convert(
    const float* __restrict__ lig_feat, const float* __restrict__ rec_feat,
    unsigned short* __restrict__ lig_swz, unsigned short* __restrict__ rec_swz)
{
    int idx = blockIdx.x * 256 + threadIdx.x;
    const float* src;
    unsigned short* dst;
    if (idx < LCHUNKS) {
        src = lig_feat; dst = lig_swz;
    } else {
        idx -= LCHUNKS;
        src = rec_feat; dst = rec_swz;
    }
    const int row = idx >> 8;         // 256 granules per row (EN*8)
    const int e   = (idx >> 3) & 31;
    const int gf  = idx & 7;

    const float* s = src + (((size_t)row * EN + e) * FN + gf * 8);
    const float4 v0 = *(const float4*)s;
    const float4 v1 = *(const float4*)(s + 4);

    const unsigned short q0 = __builtin_bit_cast(unsigned short, (_Float16)v0.x);
    const unsigned short q1 = __builtin_bit_cast(unsigned short, (_Float16)v0.y);
    const unsigned short q2 = __builtin_bit_cast(unsigned short, (_Float16)v0.z);
    const unsigned short q3 = __builtin_bit_cast(unsigned short, (_Float16)v0.w);
    const unsigned short q4 = __builtin_bit_cast(unsigned short, (_Float16)v1.x);
    const unsigned short q5 = __builtin_bit_cast(unsigned short, (_Float16)v1.y);
    const unsigned short q6 = __builtin_bit_cast(unsigned short, (_Float16)v1.z);
    const unsigned short q7 = __builtin_bit_cast(unsigned short, (_Float16)v1.w);
    uint4 o;
    o.x = (unsigned)q0 | ((unsigned)q1 << 16);
    o.y = (unsigned)q2 | ((unsigned)q3 << 16);
    o.z = (unsigned)q4 | ((unsigned)q5 << 16);
    o.w = (unsigned)q6 | ((unsigned)q7 << 16);

    const size_t dpos = (((size_t)row * EN + e) * 8 + (gf ^ (row & 7))) * 8; // ushort units
    *(uint4*)(dst + dpos) = o;
}

// ---------------- main kernel: double-buffered GL16 + MFMA ----------------
__global__ __launch_bounds__(512, 1) void ff_mfma(
    const unsigned short* __restrict__ lig_swz,  // [L][E][8 swz granules][8 f16]
    const unsigned short* __restrict__ rec_swz,  // [R][E][8 swz granules][8 f16]
    const float* __restrict__ lig_coord,         // [L][3]
    const float* __restrict__ rec_coord,         // [R][3]
    float* __restrict__ partial)
{
    __shared__ char lds[2 * BUFBYTES];

    const int tid  = threadIdx.x;
    const int lane = tid & 63;
    const int w    = tid >> 6;         // 0..7
    const int wl   = (w & 3) * 2;      // wave's base l-tile (0,2,4,6) of 8
    const int wr   = (w >> 2) * 4;     // wave's base r-tile (0,4) of 8
    const int lrow = lane & 15;        // A-row / B-col within 16x16 tile
    const int lk   = lane >> 4;        // k-group 0..3

    const int l0 = blockIdx.y * BLT;
    const int r0 = blockIdx.x * BRT;
    const int e0 = blockIdx.z * EH;

    // per-thread staging source offsets (hoisted)
    int soff[2];
    #pragma unroll
    for (int k = 0; k < 2; ++k) {
        const int idx = k * 512 + tid;
        soff[k] = (idx >> 3) * (EN * 128) + (idx & 7) * 16;
    }
    const char* ligb = (const char*)lig_swz + (size_t)l0 * (EN * 128);
    const char* recb = (const char*)rec_swz + (size_t)r0 * (EN * 128);

#define STAGE(b, e_) do {                                                   \
        const int ebyte_ = (e_) * 128;                                      \
        _Pragma("unroll")                                                   \
        for (int k_ = 0; k_ < 2; ++k_) {                                    \
            const int idx_ = k_ * 512 + tid;                                \
            GL16(ligb + soff[k_] + ebyte_, lds + (b) * BUFBYTES + idx_ * 16);            \
            GL16(recb + soff[k_] + ebyte_, lds + (b) * BUFBYTES + BPLANE + idx_ * 16);   \
        }                                                                   \
    } while (0)

    // ---- distances -> pre-scaled t' = SQK*(d - mu_{e0}), reused across EH ----
    // C/D layout (m89-verified): col = lane&15 (-> r), row = (lane>>4)*4 + reg (-> l)
    float rcx[4], rcy[4], rcz[4];
    #pragma unroll
    for (int tj = 0; tj < 4; ++tj) {
        const int r = r0 + (wr + tj) * 16 + lrow;
        rcx[tj] = rec_coord[r * 3 + 0];
        rcy[tj] = rec_coord[r * 3 + 1];
        rcz[tj] = rec_coord[r * 3 + 2];
    }
    const float mu0s = -SQK * MU_STEP * (float)e0;   // -SQK*mu_{e0}
    float t[2][4][4];   // [ti][tj][reg]
    #pragma unroll
    for (int ti = 0; ti < 2; ++ti) {
        #pragma unroll
        for (int i = 0; i < 4; ++i) {
            const int l = l0 + (wl + ti) * 16 + lk * 4 + i;
            const float lx = lig_coord[l * 3 + 0];
            const float ly = lig_coord[l * 3 + 1];
            const float lz = lig_coord[l * 3 + 2];
            #pragma unroll
            for (int tj = 0; tj < 4; ++tj) {
                const float dx = lx - rcx[tj];
                const float dy = ly - rcy[tj];
                const float dz = lz - rcz[tj];
                const float d = sqrtf(fmaf(dx, dx, fmaf(dy, dy, dz * dz)));
                t[ti][tj][i] = fmaf(SQK, d, mu0s);
            }
        }
    }

    // ---- pipeline prologue: stage e0 into buf0 ----
    STAGE(0, e0);
    __syncthreads();   // auto vmcnt(0): buf0 valid

    float usum = 0.0f;

    for (int ee = 0; ee < EH; ++ee) {
        const int cur = ee & 1;
        const int e   = e0 + ee;

        // ---- issue next-e stage into the other buffer (flies over compute) ----
        if (ee + 1 < EH) STAGE(cur ^ 1, e + 1);

        // ---- compute from buf[cur] ----
        const char* base = lds + cur * BUFBYTES;

        f32x4 acc[2][4];
        #pragma unroll
        for (int ti = 0; ti < 2; ++ti)
            #pragma unroll
            for (int tj = 0; tj < 4; ++tj)
                acc[ti][tj] = (f32x4){0.f, 0.f, 0.f, 0.f};

        #pragma unroll
        for (int kc = 0; kc < 2; ++kc) {
            const int inrow = (kc * 64 + lk * 16) ^ ((lrow & 7) << 4);
            half8 af[2], bf_[4];
            #pragma unroll
            for (int tt = 0; tt < 2; ++tt) {
                const int arow = (wl + tt) * 16 + lrow;
                af[tt] = *(const half8*)(base + arow * 128 + inrow);
            }
            #pragma unroll
            for (int tt = 0; tt < 4; ++tt) {
                const int brow = (wr + tt) * 16 + lrow;
                bf_[tt] = *(const half8*)(base + BPLANE + brow * 128 + inrow);
            }
            #pragma unroll
            for (int ti = 0; ti < 2; ++ti) {
                #pragma unroll
                for (int tj = 0; tj < 4; ++tj) {
                    acc[ti][tj] = __builtin_amdgcn_mfma_f32_16x16x32_f16(
                        af[ti], bf_[tj], acc[ti][tj], 0, 0, 0);
                }
            }
        }

        // ---- rbf weight + accumulate: u = t'^2; w = exp2(-u); fma; t' -= SDLT ----
        #pragma unroll
        for (int ti = 0; ti < 2; ++ti) {
            #pragma unroll
            for (int tj = 0; tj < 4; ++tj) {
                #pragma unroll
                for (int i = 0; i < 4; ++i) {
                    const float u = t[ti][tj][i] * t[ti][tj][i];
                    const float wgt = __builtin_amdgcn_exp2f(-u);
                    usum = fmaf(acc[ti][tj][i], wgt, usum);
                    t[ti][tj][i] -= SDLT;
                }
            }
        }

        // one barrier per e: drains this iter's stage loads and protects buffers
        __syncthreads();
    }

    // ---- block reduction (reuse LDS; safe after the loop's final barrier) ----
    float* red = (float*)lds;
    red[tid] = usum;
    __syncthreads();
    #pragma unroll
    for (int st = 256; st > 0; st >>= 1) {
        if (tid < st) red[tid] += red[tid + st];
        __syncthreads();
    }
    if (tid == 0) {
        const int bidx = (blockIdx.z * gridDim.y + blockIdx.y) * gridDim.x + blockIdx.x;
        partial[bidx] = red[0];
    }
#undef STAGE
}

__global__ __launch_bounds__(256) void ff_reduce(
    const float* __restrict__ partial, float* __restrict__ out, int n)
{
    __shared__ float s[256];
    float v = 0.0f;
    for (int i = threadIdx.x; i < n; i += 256) v += partial[i];
    s[threadIdx.x] = v;
    __syncthreads();
    #pragma unroll
    for (int st = 128; st > 0; st >>= 1) {
        if (threadIdx.x < st) s[threadIdx.x] += s[threadIdx.x + st];
        __syncthreads();
    }
    if (threadIdx.x == 0) out[0] = s[0] * 0.01f;
}

extern "C" void kernel_launch(void* const* d_in, const int* in_sizes, int n_in,
                              void* d_out, int out_size, void* d_ws, size_t ws_size,
                              hipStream_t stream)
{
    const float* lig_feat  = (const float*)d_in[0];
    const float* rec_feat  = (const float*)d_in[1];
    const float* lig_coord = (const float*)d_in[2];
    const float* rec_coord = (const float*)d_in[3];
    float* out = (float*)d_out;

    unsigned short* lig_swz = (unsigned short*)((char*)d_ws + WS_LIG);
    unsigned short* rec_swz = (unsigned short*)((char*)d_ws + WS_REC);
    float* partial          = (float*)((char*)d_ws + WS_PART);

    // 1) one-time fp32 -> swizzled f16 conversion (BW-floor ~9 us)
    const int nChunks = LCHUNKS + RCHUNKS;           // 1,179,648
    ff_convert<<<nChunks / 256, 256, 0, stream>>>(lig_feat, rec_feat, lig_swz, rec_swz);

    // 2) main MFMA kernel, double-buffered pipeline
    const dim3 grid(RN / BRT, LN / BLT, EN / EH);    // (32, 4, 4) = 512 blocks
    ff_mfma<<<grid, dim3(512), 0, stream>>>(lig_swz, rec_swz, lig_coord, rec_coord, partial);

    // 3) final reduction
    const int nPartial = (RN / BRT) * (LN / BLT) * (EN / EH);   // 512
    ff_reduce<<<1, 256, 0, stream>>>(partial, out, nPartial);
}